// Round 1
// baseline (765.003 us; speedup 1.0000x reference)
//
#include <hip/hip_runtime.h>

#define LDS_XPAD 68

__global__ void init_deg_kernel(float* da, float* db, int n) {
    int i = blockIdx.x * blockDim.x + threadIdx.x;
    if (i < n) { da[i] = 1.0f; db[i] = 1.0f; }
}

__global__ void count_kernel(const int* __restrict__ dst, float* __restrict__ deg, int E) {
    int e = blockIdx.x * blockDim.x + threadIdx.x;
    if (e < E) atomicAdd(&deg[dst[e]], 1.0f);
}

__global__ void rsqrt_kernel(float* da, float* db, int n) {
    int i = blockIdx.x * blockDim.x + threadIdx.x;
    if (i < n) { da[i] = rsqrtf(da[i]); db[i] = rsqrtf(db[i]); }
}

// y = (X @ W) * dinv[row]; z = y (z is the scatter accumulator, init = self-loop term)
template<int M>
__global__ void gemm_scale_kernel(const float* __restrict__ X,
                                  const float* __restrict__ W,   // [64][M] row-major
                                  const float* __restrict__ dinv,
                                  float* __restrict__ y,
                                  float* __restrict__ z,
                                  int n) {
    __shared__ float xs[64 * LDS_XPAD];
    __shared__ float ws[64 * M];
    const int tid = threadIdx.x;
    const int row = tid >> 2;      // 0..63
    const int cg  = tid & 3;       // column group 0..3
    const int grow = blockIdx.x * 64 + row;

    // stage X tile: each thread loads 16 floats of its row
    {
        float4 v0, v1, v2, v3;
        if (grow < n) {
            const float4* xr = reinterpret_cast<const float4*>(X + (size_t)grow * 64 + cg * 16);
            v0 = xr[0]; v1 = xr[1]; v2 = xr[2]; v3 = xr[3];
        } else {
            v0 = v1 = v2 = v3 = make_float4(0.f, 0.f, 0.f, 0.f);
        }
        float4* xd = reinterpret_cast<float4*>(&xs[row * LDS_XPAD + cg * 16]);
        xd[0] = v0; xd[1] = v1; xd[2] = v2; xd[3] = v3;
    }
    // stage W (64*M floats, flat copy)
    {
        const float4* wsrc = reinterpret_cast<const float4*>(W);
        float4* wdst = reinterpret_cast<float4*>(ws);
        #pragma unroll
        for (int i = 0; i < (64 * M / 4) / 256; ++i)
            wdst[tid + i * 256] = wsrc[tid + i * 256];
    }
    __syncthreads();

    constexpr int CPT = M / 4;     // 16 or 4 columns per thread
    float acc[CPT];
    #pragma unroll
    for (int j = 0; j < CPT; ++j) acc[j] = 0.0f;

    for (int k = 0; k < 64; ++k) {
        float xk = xs[row * LDS_XPAD + k];
        #pragma unroll
        for (int j = 0; j < CPT; ++j)
            acc[j] += xk * ws[k * M + cg * CPT + j];
    }

    if (grow < n) {
        float s = dinv[grow];
        float* yp = y + (size_t)grow * M + cg * CPT;
        float* zp = z + (size_t)grow * M + cg * CPT;
        #pragma unroll
        for (int j = 0; j < CPT; j += 4) {
            float4 o = make_float4(acc[j] * s, acc[j + 1] * s, acc[j + 2] * s, acc[j + 3] * s);
            *reinterpret_cast<float4*>(yp + j) = o;
            *reinterpret_cast<float4*>(zp + j) = o;
        }
    }
}

// z[dst] += y[src] over edges; F = 1<<LOGF features per row
template<int LOGF>
__global__ void scatter_kernel(const int* __restrict__ src, const int* __restrict__ dst,
                               const float* __restrict__ y, float* __restrict__ z, int E) {
    const long long idx = (long long)blockIdx.x * blockDim.x + threadIdx.x;
    const int e = (int)(idx >> LOGF);
    const int f = (int)(idx & ((1 << LOGF) - 1));
    if (e < E) {
        const int s = src[e];
        const int d = dst[e];
        atomicAdd(&z[((size_t)d << LOGF) + f], y[((size_t)s << LOGF) + f]);
    }
}

// out[i,f] = z[i,f] * dinv[i]
template<int LOGF>
__global__ void rowscale_kernel(const float* __restrict__ z, const float* __restrict__ dinv,
                                float* __restrict__ outp, int n) {
    const long long idx = (long long)blockIdx.x * blockDim.x + threadIdx.x;
    const int i = (int)(idx >> LOGF);
    if (i < n) outp[idx] = z[idx] * dinv[i];
}

// h = relu(0.5*(acc + z*dinv_b[i] + ba[f] + bb[f]))
__global__ void combine_relu_kernel(const float* __restrict__ acc, const float* __restrict__ z,
                                    const float* __restrict__ dinvb,
                                    const float* __restrict__ ba, const float* __restrict__ bb,
                                    float* __restrict__ h, int n) {
    const long long idx = (long long)blockIdx.x * blockDim.x + threadIdx.x;
    const int i = (int)(idx >> 6);
    const int f = (int)(idx & 63);
    if (i < n) {
        float v = 0.5f * (acc[idx] + z[idx] * dinvb[i] + ba[f] + bb[f]);
        h[idx] = fmaxf(v, 0.0f);
    }
}

__global__ void combine_out_kernel(const float* __restrict__ acc, const float* __restrict__ z,
                                   const float* __restrict__ dinvb,
                                   const float* __restrict__ ba, const float* __restrict__ bb,
                                   float* __restrict__ outp, int n) {
    const long long idx = (long long)blockIdx.x * blockDim.x + threadIdx.x;
    const int i = (int)(idx >> 4);
    const int f = (int)(idx & 15);
    if (i < n) outp[idx] = 0.5f * (acc[idx] + z[idx] * dinvb[i] + ba[f] + bb[f]);
}

extern "C" void kernel_launch(void* const* d_in, const int* in_sizes, int n_in,
                              void* d_out, int out_size, void* d_ws, size_t ws_size,
                              hipStream_t stream) {
    const float* x   = (const float*)d_in[0];
    const int*   eia = (const int*)d_in[1];
    const int*   eib = (const int*)d_in[2];
    const float* W1a = (const float*)d_in[3];
    const float* b1a = (const float*)d_in[4];
    const float* W1b = (const float*)d_in[5];
    const float* b1b = (const float*)d_in[6];
    const float* W2a = (const float*)d_in[7];
    const float* b2a = (const float*)d_in[8];
    const float* W2b = (const float*)d_in[9];
    const float* b2b = (const float*)d_in[10];
    float* out = (float*)d_out;

    const int n  = in_sizes[0] / 64;
    const int Ea = in_sizes[1] / 2;
    const int Eb = in_sizes[2] / 2;

    float* wsf    = (float*)d_ws;
    float* dinv_a = wsf;
    float* dinv_b = wsf + n;
    float* A = wsf + 2 * (size_t)n;        // 64N: y (gather source)
    float* B = A + 64 * (size_t)n;         // 64N: z (scatter accumulator)
    float* C = B + 64 * (size_t)n;         // 64N: acc / h

    const int T = 256;
    auto cdiv = [](long long a, long long b) { return (unsigned)((a + b - 1) / b); };

    // degrees (self-loop folded into init=1) -> dinv
    init_deg_kernel<<<cdiv(n, T), T, 0, stream>>>(dinv_a, dinv_b, n);
    count_kernel<<<cdiv(Ea, T), T, 0, stream>>>(eia + Ea, dinv_a, Ea);
    count_kernel<<<cdiv(Eb, T), T, 0, stream>>>(eib + Eb, dinv_b, Eb);
    rsqrt_kernel<<<cdiv(n, T), T, 0, stream>>>(dinv_a, dinv_b, n);

    // ---- layer 1, relation a ----
    gemm_scale_kernel<64><<<cdiv(n, 64), T, 0, stream>>>(x, W1a, dinv_a, A, B, n);
    scatter_kernel<6><<<cdiv((long long)Ea * 64, T), T, 0, stream>>>(eia, eia + Ea, A, B, Ea);
    rowscale_kernel<6><<<cdiv((long long)n * 64, T), T, 0, stream>>>(B, dinv_a, C, n);
    // ---- layer 1, relation b ----
    gemm_scale_kernel<64><<<cdiv(n, 64), T, 0, stream>>>(x, W1b, dinv_b, A, B, n);
    scatter_kernel<6><<<cdiv((long long)Eb * 64, T), T, 0, stream>>>(eib, eib + Eb, A, B, Eb);
    combine_relu_kernel<<<cdiv((long long)n * 64, T), T, 0, stream>>>(C, B, dinv_b, b1a, b1b, C, n);

    // ---- layer 2 (h = C) ----
    float* y2   = A;
    float* z2   = B;
    float* acc2 = A + 16 * (size_t)n;
    gemm_scale_kernel<16><<<cdiv(n, 64), T, 0, stream>>>(C, W2a, dinv_a, y2, z2, n);
    scatter_kernel<4><<<cdiv((long long)Ea * 16, T), T, 0, stream>>>(eia, eia + Ea, y2, z2, Ea);
    rowscale_kernel<4><<<cdiv((long long)n * 16, T), T, 0, stream>>>(z2, dinv_a, acc2, n);
    gemm_scale_kernel<16><<<cdiv(n, 64), T, 0, stream>>>(C, W2b, dinv_b, y2, z2, n);
    scatter_kernel<4><<<cdiv((long long)Eb * 16, T), T, 0, stream>>>(eib, eib + Eb, y2, z2, Eb);
    combine_out_kernel<<<cdiv((long long)n * 16, T), T, 0, stream>>>(acc2, z2, dinv_b, b2a, b2b, out, n);
}

// Round 2
// 546.132 us; speedup vs baseline: 1.4008x; 1.4008x over previous
//
#include <hip/hip_runtime.h>

#define LDS_XPAD 68

__global__ void zero_int_kernel(int* p, int n) {
    int i = blockIdx.x * blockDim.x + threadIdx.x;
    if (i < n) p[i] = 0;
}

__global__ void hist_kernel(const int* __restrict__ dst, int* __restrict__ deg, int E) {
    int e = blockIdx.x * blockDim.x + threadIdx.x;
    if (e < E) atomicAdd(&deg[dst[e]], 1);
}

// block-level exclusive scan of deg -> rowptr (block-local), block sums -> partials
__global__ void scan1_kernel(const int* __restrict__ deg, int* __restrict__ rowptr,
                             int* __restrict__ partials, int n) {
    __shared__ int s[256];
    int i = blockIdx.x * 256 + threadIdx.x;
    int v = (i < n) ? deg[i] : 0;
    s[threadIdx.x] = v;
    __syncthreads();
    #pragma unroll
    for (int d = 1; d < 256; d <<= 1) {
        int t = (threadIdx.x >= d) ? s[threadIdx.x - d] : 0;
        __syncthreads();
        s[threadIdx.x] += t;
        __syncthreads();
    }
    if (i < n) rowptr[i] = s[threadIdx.x] - v;   // exclusive
    if (threadIdx.x == 255) partials[blockIdx.x] = s[255];
}

__global__ void scan2_kernel(int* partials, int nb) {
    if (blockIdx.x == 0 && threadIdx.x == 0) {
        int acc = 0;
        for (int i = 0; i < nb; ++i) { int t = partials[i]; partials[i] = acc; acc += t; }
    }
}

__global__ void scan3_kernel(int* __restrict__ rowptr, const int* __restrict__ partials,
                             int* __restrict__ cursor, const int* __restrict__ deg,
                             float* __restrict__ dinv, int n, int E) {
    int i = blockIdx.x * 256 + threadIdx.x;
    if (i < n) {
        int v = rowptr[i] + partials[blockIdx.x];
        rowptr[i] = v;
        cursor[i] = v;
        dinv[i] = rsqrtf((float)(deg[i] + 1));   // +1 = self-loop
    }
    if (i == 0) rowptr[n] = E;
}

__global__ void fill_kernel(const int* __restrict__ src, const int* __restrict__ dst,
                            int* __restrict__ cursor, int* __restrict__ col, int E) {
    int e = blockIdx.x * blockDim.x + threadIdx.x;
    if (e < E) {
        int pos = atomicAdd(&cursor[dst[e]], 1);
        col[pos] = src[e];
    }
}

// y = (X @ W) * dinv[row]
template<int M>
__global__ void gemm_scale_kernel(const float* __restrict__ X,
                                  const float* __restrict__ W,   // [64][M] row-major
                                  const float* __restrict__ dinv,
                                  float* __restrict__ y,
                                  int n) {
    __shared__ float xs[64 * LDS_XPAD];
    __shared__ float ws[64 * M];
    const int tid = threadIdx.x;
    const int row = tid >> 2;
    const int cg  = tid & 3;
    const int grow = blockIdx.x * 64 + row;

    {
        float4 v0, v1, v2, v3;
        if (grow < n) {
            const float4* xr = reinterpret_cast<const float4*>(X + (size_t)grow * 64 + cg * 16);
            v0 = xr[0]; v1 = xr[1]; v2 = xr[2]; v3 = xr[3];
        } else {
            v0 = v1 = v2 = v3 = make_float4(0.f, 0.f, 0.f, 0.f);
        }
        float4* xd = reinterpret_cast<float4*>(&xs[row * LDS_XPAD + cg * 16]);
        xd[0] = v0; xd[1] = v1; xd[2] = v2; xd[3] = v3;
    }
    {
        const float4* wsrc = reinterpret_cast<const float4*>(W);
        float4* wdst = reinterpret_cast<float4*>(ws);
        #pragma unroll
        for (int i = 0; i < (64 * M / 4) / 256; ++i)
            wdst[tid + i * 256] = wsrc[tid + i * 256];
    }
    __syncthreads();

    constexpr int CPT = M / 4;
    float acc[CPT];
    #pragma unroll
    for (int j = 0; j < CPT; ++j) acc[j] = 0.0f;

    for (int k = 0; k < 64; ++k) {
        float xk = xs[row * LDS_XPAD + k];
        #pragma unroll
        for (int j = 0; j < CPT; ++j)
            acc[j] += xk * ws[k * M + cg * CPT + j];
    }

    if (grow < n) {
        float s = dinv[grow];
        float* yp = y + (size_t)grow * M + cg * CPT;
        #pragma unroll
        for (int j = 0; j < CPT; j += 4) {
            float4 o = make_float4(acc[j] * s, acc[j + 1] * s, acc[j + 2] * s, acc[j + 3] * s);
            *reinterpret_cast<float4*>(yp + j) = o;
        }
    }
}

// Gather-aggregate, F=64: one wave per node, lane = feature.
// MODE 0: out = dinv[i]*(y[i] + sum y[col])
// MODE 1: out = relu(0.5*(other + dinv[i]*sum + ba[f] + bb[f]))
template<int MODE>
__global__ void agg64_kernel(const float* __restrict__ y,
                             const int* __restrict__ rowptr,
                             const int* __restrict__ col,
                             const float* __restrict__ dinv,
                             const float* __restrict__ other,
                             const float* __restrict__ ba, const float* __restrict__ bb,
                             float* __restrict__ outp, int n) {
    const int lane = threadIdx.x & 63;
    const int wid  = (blockIdx.x * blockDim.x + threadIdx.x) >> 6;
    const int nw   = (gridDim.x * blockDim.x) >> 6;
    for (int i = wid; i < n; i += nw) {
        float acc = y[(size_t)i * 64 + lane];
        const int e0 = rowptr[i], e1 = rowptr[i + 1];
        int e = e0;
        for (; e + 4 <= e1; e += 4) {
            int s0 = col[e], s1 = col[e + 1], s2 = col[e + 2], s3 = col[e + 3];
            float g0 = y[(size_t)s0 * 64 + lane];
            float g1 = y[(size_t)s1 * 64 + lane];
            float g2 = y[(size_t)s2 * 64 + lane];
            float g3 = y[(size_t)s3 * 64 + lane];
            acc += g0 + g1 + g2 + g3;
        }
        for (; e < e1; ++e) acc += y[(size_t)col[e] * 64 + lane];
        float v = acc * dinv[i];
        if (MODE == 0) {
            outp[(size_t)i * 64 + lane] = v;
        } else {
            float r = 0.5f * (other[(size_t)i * 64 + lane] + v + ba[lane] + bb[lane]);
            outp[(size_t)i * 64 + lane] = fmaxf(r, 0.0f);
        }
    }
}

// Gather-aggregate, F=16: 16 lanes per node (4 nodes per wave).
// MODE 0: out = dinv[i]*(y[i] + sum)   MODE 1: out = 0.5*(other + dinv[i]*sum + ba + bb)
template<int MODE>
__global__ void agg16_kernel(const float* __restrict__ y,
                             const int* __restrict__ rowptr,
                             const int* __restrict__ col,
                             const float* __restrict__ dinv,
                             const float* __restrict__ other,
                             const float* __restrict__ ba, const float* __restrict__ bb,
                             float* __restrict__ outp, int n) {
    const int lane = threadIdx.x & 15;
    const int gid  = (blockIdx.x * blockDim.x + threadIdx.x) >> 4;
    const int ng   = (gridDim.x * blockDim.x) >> 4;
    for (int i = gid; i < n; i += ng) {
        float acc = y[(size_t)i * 16 + lane];
        const int e0 = rowptr[i], e1 = rowptr[i + 1];
        int e = e0;
        for (; e + 4 <= e1; e += 4) {
            int s0 = col[e], s1 = col[e + 1], s2 = col[e + 2], s3 = col[e + 3];
            float g0 = y[(size_t)s0 * 16 + lane];
            float g1 = y[(size_t)s1 * 16 + lane];
            float g2 = y[(size_t)s2 * 16 + lane];
            float g3 = y[(size_t)s3 * 16 + lane];
            acc += g0 + g1 + g2 + g3;
        }
        for (; e < e1; ++e) acc += y[(size_t)col[e] * 16 + lane];
        float v = acc * dinv[i];
        if (MODE == 0) {
            outp[(size_t)i * 16 + lane] = v;
        } else {
            outp[(size_t)i * 16 + lane] = 0.5f * (other[(size_t)i * 16 + lane] + v + ba[lane] + bb[lane]);
        }
    }
}

extern "C" void kernel_launch(void* const* d_in, const int* in_sizes, int n_in,
                              void* d_out, int out_size, void* d_ws, size_t ws_size,
                              hipStream_t stream) {
    const float* x   = (const float*)d_in[0];
    const int*   eia = (const int*)d_in[1];
    const int*   eib = (const int*)d_in[2];
    const float* W1a = (const float*)d_in[3];
    const float* b1a = (const float*)d_in[4];
    const float* W1b = (const float*)d_in[5];
    const float* b1b = (const float*)d_in[6];
    const float* W2a = (const float*)d_in[7];
    const float* b2a = (const float*)d_in[8];
    const float* W2b = (const float*)d_in[9];
    const float* b2b = (const float*)d_in[10];
    float* out = (float*)d_out;

    const int n  = in_sizes[0] / 64;
    const int Ea = in_sizes[1] / 2;
    const int Eb = in_sizes[2] / 2;

    // workspace layout (4-byte elements)
    char* wsp = (char*)d_ws;
    size_t off = 0;
    auto carve = [&](size_t elems) { void* p = wsp + off; off += ((elems + 3) & ~(size_t)3) * 4; return p; };
    float* dinv_a  = (float*)carve(n);
    float* dinv_b  = (float*)carve(n);
    int*   rowptr_a = (int*)carve(n + 1);
    int*   rowptr_b = (int*)carve(n + 1);
    int*   deg     = (int*)carve(n);
    int*   cursor  = (int*)carve(n);
    int*   partials = (int*)carve(1024);
    int*   col_a   = (int*)carve(Ea);
    int*   col_b   = (int*)carve(Eb);
    float* y       = (float*)carve((size_t)64 * n);   // also y2 (16n) + D (16n at +32n)
    float* C       = (float*)carve((size_t)64 * n);   // layer-1 acc / h (in place)
    float* y2 = y;
    float* D  = y + (size_t)32 * n;                   // layer-2 rel-a result

    const int T = 256;
    auto cdiv = [](long long a, long long b) { return (unsigned)((a + b - 1) / b); };
    const unsigned nb = cdiv(n, 256);

    // ---- CSR build, relation a ----
    zero_int_kernel<<<cdiv(n, T), T, 0, stream>>>(deg, n);
    hist_kernel<<<cdiv(Ea, T), T, 0, stream>>>(eia + Ea, deg, Ea);
    scan1_kernel<<<nb, 256, 0, stream>>>(deg, rowptr_a, partials, n);
    scan2_kernel<<<1, 64, 0, stream>>>(partials, nb);
    scan3_kernel<<<nb, 256, 0, stream>>>(rowptr_a, partials, cursor, deg, dinv_a, n, Ea);
    fill_kernel<<<cdiv(Ea, T), T, 0, stream>>>(eia, eia + Ea, cursor, col_a, Ea);
    // ---- CSR build, relation b ----
    zero_int_kernel<<<cdiv(n, T), T, 0, stream>>>(deg, n);
    hist_kernel<<<cdiv(Eb, T), T, 0, stream>>>(eib + Eb, deg, Eb);
    scan1_kernel<<<nb, 256, 0, stream>>>(deg, rowptr_b, partials, n);
    scan2_kernel<<<1, 64, 0, stream>>>(partials, nb);
    scan3_kernel<<<nb, 256, 0, stream>>>(rowptr_b, partials, cursor, deg, dinv_b, n, Eb);
    fill_kernel<<<cdiv(Eb, T), T, 0, stream>>>(eib, eib + Eb, cursor, col_b, Eb);

    const unsigned AGG_GRID = 2048;

    // ---- layer 1 ----
    gemm_scale_kernel<64><<<cdiv(n, 64), T, 0, stream>>>(x, W1a, dinv_a, y, n);
    agg64_kernel<0><<<AGG_GRID, T, 0, stream>>>(y, rowptr_a, col_a, dinv_a, nullptr, nullptr, nullptr, C, n);
    gemm_scale_kernel<64><<<cdiv(n, 64), T, 0, stream>>>(x, W1b, dinv_b, y, n);
    agg64_kernel<1><<<AGG_GRID, T, 0, stream>>>(y, rowptr_b, col_b, dinv_b, C, b1a, b1b, C, n);

    // ---- layer 2 (input = C) ----
    gemm_scale_kernel<16><<<cdiv(n, 64), T, 0, stream>>>(C, W2a, dinv_a, y2, n);
    agg16_kernel<0><<<AGG_GRID, T, 0, stream>>>(y2, rowptr_a, col_a, dinv_a, nullptr, nullptr, nullptr, D, n);
    gemm_scale_kernel<16><<<cdiv(n, 64), T, 0, stream>>>(C, W2b, dinv_b, y2, n);
    agg16_kernel<1><<<AGG_GRID, T, 0, stream>>>(y2, rowptr_b, col_b, dinv_b, D, b2a, b2b, out, n);
}

// Round 3
// 483.545 us; speedup vs baseline: 1.5821x; 1.1294x over previous
//
#include <hip/hip_runtime.h>

#define LDS_XPAD 68
#define MAXBUK 256
#define BF_CHUNK 2048

__global__ void zero_int_kernel(int* p, int n) {
    int i = blockIdx.x * blockDim.x + threadIdx.x;
    if (i < n) p[i] = 0;
}

__global__ void hist_kernel(const int* __restrict__ dst, int* __restrict__ deg, int E) {
    int e = blockIdx.x * blockDim.x + threadIdx.x;
    if (e < E) atomicAdd(&deg[dst[e]], 1);
}

// ---- bucket binning (radix by dst>>shift) ----
__global__ void bhist_kernel(const int* __restrict__ dst, int* __restrict__ bcnt,
                             int E, int shift, int nbuk) {
    __shared__ int h[MAXBUK];
    for (int i = threadIdx.x; i < nbuk; i += blockDim.x) h[i] = 0;
    __syncthreads();
    int stride = gridDim.x * blockDim.x;
    for (int e = blockIdx.x * blockDim.x + threadIdx.x; e < E; e += stride)
        atomicAdd(&h[dst[e] >> shift], 1);
    __syncthreads();
    for (int i = threadIdx.x; i < nbuk; i += blockDim.x)
        if (h[i]) atomicAdd(&bcnt[i], h[i]);
}

__global__ void bscan_kernel(const int* __restrict__ bcnt, int* __restrict__ bcursor, int nbuk) {
    __shared__ int s[256];
    int t = threadIdx.x;
    int v = (t < nbuk) ? bcnt[t] : 0;
    s[t] = v;
    __syncthreads();
    #pragma unroll
    for (int d = 1; d < 256; d <<= 1) {
        int u = (t >= d) ? s[t - d] : 0;
        __syncthreads();
        s[t] += u;
        __syncthreads();
    }
    if (t < nbuk) bcursor[t] = s[t] - v;   // exclusive
}

__global__ void bfill_kernel(const int* __restrict__ src, const int* __restrict__ dst,
                             int* __restrict__ bcursor, int2* __restrict__ pairs,
                             int E, int shift, int nbuk) {
    __shared__ int cnt[MAXBUK];
    __shared__ int base[MAXBUK];
    __shared__ int off[MAXBUK];
    const int t = threadIdx.x;
    const long long e0 = (long long)blockIdx.x * BF_CHUNK;
    const int nedge = (int)min((long long)BF_CHUNK, (long long)E - e0);
    for (int i = t; i < nbuk; i += 256) cnt[i] = 0;
    __syncthreads();
    for (int i = t; i < nedge; i += 256) atomicAdd(&cnt[dst[e0 + i] >> shift], 1);
    __syncthreads();
    for (int i = t; i < nbuk; i += 256) {
        off[i] = 0;
        base[i] = cnt[i] ? atomicAdd(&bcursor[i], cnt[i]) : 0;
    }
    __syncthreads();
    for (int i = t; i < nedge; i += 256) {
        int d = dst[e0 + i];
        int b = d >> shift;
        int p = base[b] + atomicAdd(&off[b], 1);
        pairs[p] = make_int2(src[e0 + i], d);
    }
}

// local CSR fill from bucket-ordered pairs: writes land in small hot windows
__global__ void lfill_kernel(const int2* __restrict__ pairs, int* __restrict__ cursor,
                             int* __restrict__ col, int E) {
    int e = blockIdx.x * blockDim.x + threadIdx.x;
    if (e < E) {
        int2 p = pairs[e];
        int pos = atomicAdd(&cursor[p.y], 1);
        col[pos] = p.x;
    }
}

// ---- node-count scan -> rowptr / cursor / dinv ----
__global__ void scan1_kernel(const int* __restrict__ deg, int* __restrict__ rowptr,
                             int* __restrict__ partials, int n) {
    __shared__ int s[256];
    int i = blockIdx.x * 256 + threadIdx.x;
    int v = (i < n) ? deg[i] : 0;
    s[threadIdx.x] = v;
    __syncthreads();
    #pragma unroll
    for (int d = 1; d < 256; d <<= 1) {
        int t = (threadIdx.x >= d) ? s[threadIdx.x - d] : 0;
        __syncthreads();
        s[threadIdx.x] += t;
        __syncthreads();
    }
    if (i < n) rowptr[i] = s[threadIdx.x] - v;
    if (threadIdx.x == 255) partials[blockIdx.x] = s[255];
}

__global__ void scan2_kernel(int* partials, int nb) {
    int lane = threadIdx.x;              // 64 threads, one wave
    int acc = 0;
    for (int base = 0; base < nb; base += 64) {
        int i = base + lane;
        int v = (i < nb) ? partials[i] : 0;
        int s = v;
        #pragma unroll
        for (int d = 1; d < 64; d <<= 1) {
            int t = __shfl_up(s, d);
            if (lane >= d) s += t;
        }
        if (i < nb) partials[i] = acc + s - v;
        acc += __shfl(s, 63);
    }
}

__global__ void scan3_kernel(int* __restrict__ rowptr, const int* __restrict__ partials,
                             int* __restrict__ cursor, const int* __restrict__ deg,
                             float* __restrict__ dinv, int n, int E) {
    int i = blockIdx.x * 256 + threadIdx.x;
    if (i < n) {
        int v = rowptr[i] + partials[blockIdx.x];
        rowptr[i] = v;
        cursor[i] = v;
        dinv[i] = rsqrtf((float)(deg[i] + 1));
    }
    if (i == 0) rowptr[n] = E;
}

// ---- dual-weight GEMM: ya = (X@Wa)*dinva[row], yb = (X@Wb)*dinvb[row] ----
template<int M>
__global__ void gemm2_scale_kernel(const float* __restrict__ X,
                                   const float* __restrict__ Wa, const float* __restrict__ Wb,
                                   const float* __restrict__ dinva, const float* __restrict__ dinvb,
                                   float* __restrict__ ya, float* __restrict__ yb, int n) {
    __shared__ float xs[64 * LDS_XPAD];
    __shared__ float wsa[64 * M];
    __shared__ float wsb[64 * M];
    const int tid = threadIdx.x;
    const int row = tid >> 2;
    const int cg  = tid & 3;
    const int grow = blockIdx.x * 64 + row;

    {
        float4 v0, v1, v2, v3;
        if (grow < n) {
            const float4* xr = reinterpret_cast<const float4*>(X + (size_t)grow * 64 + cg * 16);
            v0 = xr[0]; v1 = xr[1]; v2 = xr[2]; v3 = xr[3];
        } else {
            v0 = v1 = v2 = v3 = make_float4(0.f, 0.f, 0.f, 0.f);
        }
        float4* xd = reinterpret_cast<float4*>(&xs[row * LDS_XPAD + cg * 16]);
        xd[0] = v0; xd[1] = v1; xd[2] = v2; xd[3] = v3;
    }
    {
        const float4* sa = reinterpret_cast<const float4*>(Wa);
        const float4* sb = reinterpret_cast<const float4*>(Wb);
        float4* da = reinterpret_cast<float4*>(wsa);
        float4* db = reinterpret_cast<float4*>(wsb);
        #pragma unroll
        for (int i = 0; i < (64 * M / 4 + 255) / 256; ++i) {
            int idx = tid + i * 256;
            if (idx < 64 * M / 4) { da[idx] = sa[idx]; db[idx] = sb[idx]; }
        }
    }
    __syncthreads();

    constexpr int CPT = M / 4;
    float acca[CPT], accb[CPT];
    #pragma unroll
    for (int j = 0; j < CPT; ++j) { acca[j] = 0.0f; accb[j] = 0.0f; }

    for (int k = 0; k < 64; ++k) {
        float xk = xs[row * LDS_XPAD + k];
        #pragma unroll
        for (int j = 0; j < CPT; ++j) {
            acca[j] += xk * wsa[k * M + cg * CPT + j];
            accb[j] += xk * wsb[k * M + cg * CPT + j];
        }
    }

    if (grow < n) {
        float sa = dinva[grow], sb = dinvb[grow];
        float* pa = ya + (size_t)grow * M + cg * CPT;
        float* pb = yb + (size_t)grow * M + cg * CPT;
        #pragma unroll
        for (int j = 0; j < CPT; j += 4) {
            *reinterpret_cast<float4*>(pa + j) =
                make_float4(acca[j] * sa, acca[j + 1] * sa, acca[j + 2] * sa, acca[j + 3] * sa);
            *reinterpret_cast<float4*>(pb + j) =
                make_float4(accb[j] * sb, accb[j + 1] * sb, accb[j + 2] * sb, accb[j + 3] * sb);
        }
    }
}

// single-weight fallback (ws-constrained path)
template<int M>
__global__ void gemm_scale_kernel(const float* __restrict__ X,
                                  const float* __restrict__ W,
                                  const float* __restrict__ dinv,
                                  float* __restrict__ y, int n) {
    __shared__ float xs[64 * LDS_XPAD];
    __shared__ float ws[64 * M];
    const int tid = threadIdx.x;
    const int row = tid >> 2;
    const int cg  = tid & 3;
    const int grow = blockIdx.x * 64 + row;
    {
        float4 v0, v1, v2, v3;
        if (grow < n) {
            const float4* xr = reinterpret_cast<const float4*>(X + (size_t)grow * 64 + cg * 16);
            v0 = xr[0]; v1 = xr[1]; v2 = xr[2]; v3 = xr[3];
        } else {
            v0 = v1 = v2 = v3 = make_float4(0.f, 0.f, 0.f, 0.f);
        }
        float4* xd = reinterpret_cast<float4*>(&xs[row * LDS_XPAD + cg * 16]);
        xd[0] = v0; xd[1] = v1; xd[2] = v2; xd[3] = v3;
    }
    {
        const float4* wsrc = reinterpret_cast<const float4*>(W);
        float4* wdst = reinterpret_cast<float4*>(ws);
        #pragma unroll
        for (int i = 0; i < (64 * M / 4 + 255) / 256; ++i) {
            int idx = tid + i * 256;
            if (idx < 64 * M / 4) wdst[idx] = wsrc[idx];
        }
    }
    __syncthreads();
    constexpr int CPT = M / 4;
    float acc[CPT];
    #pragma unroll
    for (int j = 0; j < CPT; ++j) acc[j] = 0.0f;
    for (int k = 0; k < 64; ++k) {
        float xk = xs[row * LDS_XPAD + k];
        #pragma unroll
        for (int j = 0; j < CPT; ++j) acc[j] += xk * ws[k * M + cg * CPT + j];
    }
    if (grow < n) {
        float s = dinv[grow];
        float* yp = y + (size_t)grow * M + cg * CPT;
        #pragma unroll
        for (int j = 0; j < CPT; j += 4)
            *reinterpret_cast<float4*>(yp + j) =
                make_float4(acc[j] * s, acc[j + 1] * s, acc[j + 2] * s, acc[j + 3] * s);
    }
}

// ---- gather aggregation ----
template<int MODE>
__global__ void agg64_kernel(const float* __restrict__ y,
                             const int* __restrict__ rowptr,
                             const int* __restrict__ col,
                             const float* __restrict__ dinv,
                             const float* __restrict__ other,
                             const float* __restrict__ ba, const float* __restrict__ bb,
                             float* __restrict__ outp, int n) {
    const int lane = threadIdx.x & 63;
    const int wid  = (blockIdx.x * blockDim.x + threadIdx.x) >> 6;
    const int nw   = (gridDim.x * blockDim.x) >> 6;
    for (int i = wid; i < n; i += nw) {
        float acc = y[(size_t)i * 64 + lane];
        const int e0 = rowptr[i], e1 = rowptr[i + 1];
        int e = e0;
        for (; e + 4 <= e1; e += 4) {
            int s0 = col[e], s1 = col[e + 1], s2 = col[e + 2], s3 = col[e + 3];
            acc += y[(size_t)s0 * 64 + lane] + y[(size_t)s1 * 64 + lane]
                 + y[(size_t)s2 * 64 + lane] + y[(size_t)s3 * 64 + lane];
        }
        for (; e < e1; ++e) acc += y[(size_t)col[e] * 64 + lane];
        float v = acc * dinv[i];
        if (MODE == 0) {
            outp[(size_t)i * 64 + lane] = v;
        } else {
            float r = 0.5f * (other[(size_t)i * 64 + lane] + v + ba[lane] + bb[lane]);
            outp[(size_t)i * 64 + lane] = fmaxf(r, 0.0f);
        }
    }
}

template<int MODE>
__global__ void agg16_kernel(const float* __restrict__ y,
                             const int* __restrict__ rowptr,
                             const int* __restrict__ col,
                             const float* __restrict__ dinv,
                             const float* __restrict__ other,
                             const float* __restrict__ ba, const float* __restrict__ bb,
                             float* __restrict__ outp, int n) {
    const int lane = threadIdx.x & 15;
    const int gid  = (blockIdx.x * blockDim.x + threadIdx.x) >> 4;
    const int ng   = (gridDim.x * blockDim.x) >> 4;
    for (int i = gid; i < n; i += ng) {
        float acc = y[(size_t)i * 16 + lane];
        const int e0 = rowptr[i], e1 = rowptr[i + 1];
        int e = e0;
        for (; e + 4 <= e1; e += 4) {
            int s0 = col[e], s1 = col[e + 1], s2 = col[e + 2], s3 = col[e + 3];
            acc += y[(size_t)s0 * 16 + lane] + y[(size_t)s1 * 16 + lane]
                 + y[(size_t)s2 * 16 + lane] + y[(size_t)s3 * 16 + lane];
        }
        for (; e < e1; ++e) acc += y[(size_t)col[e] * 16 + lane];
        float v = acc * dinv[i];
        if (MODE == 0) {
            outp[(size_t)i * 16 + lane] = v;
        } else {
            outp[(size_t)i * 16 + lane] = 0.5f * (other[(size_t)i * 16 + lane] + v + ba[lane] + bb[lane]);
        }
    }
}

extern "C" void kernel_launch(void* const* d_in, const int* in_sizes, int n_in,
                              void* d_out, int out_size, void* d_ws, size_t ws_size,
                              hipStream_t stream) {
    const float* x   = (const float*)d_in[0];
    const int*   eia = (const int*)d_in[1];
    const int*   eib = (const int*)d_in[2];
    const float* W1a = (const float*)d_in[3];
    const float* b1a = (const float*)d_in[4];
    const float* W1b = (const float*)d_in[5];
    const float* b1b = (const float*)d_in[6];
    const float* W2a = (const float*)d_in[7];
    const float* b2a = (const float*)d_in[8];
    const float* W2b = (const float*)d_in[9];
    const float* b2b = (const float*)d_in[10];
    float* out = (float*)d_out;

    const int n  = in_sizes[0] / 64;
    const int Ea = in_sizes[1] / 2;
    const int Eb = in_sizes[2] / 2;
    const int Emax = Ea > Eb ? Ea : Eb;

    int shift = 9;
    while ((((long long)n + (1LL << shift) - 1) >> shift) > MAXBUK) ++shift;
    const int nbuk = (int)(((long long)n + (1LL << shift) - 1) >> shift);

    char* wsp = (char*)d_ws;
    size_t off = 0;
    auto carve = [&](size_t elems) { void* p = wsp + off; off += ((elems + 3) & ~(size_t)3) * 4; return p; };
    float* dinv_a   = (float*)carve(n);
    float* dinv_b   = (float*)carve(n);
    int*   rowptr_a = (int*)carve(n + 1);
    int*   rowptr_b = (int*)carve(n + 1);
    int*   deg      = (int*)carve(n);
    int*   cursor   = (int*)carve(n);
    int*   partials = (int*)carve(1024);
    int*   bcnt     = (int*)carve(MAXBUK);
    int*   bcursor  = (int*)carve(MAXBUK);
    int*   col_a    = (int*)carve(Ea);
    int*   col_b    = (int*)carve(Eb);
    int2*  pairs    = (int2*)carve((size_t)Emax * 2);
    size_t fixed_off = off;
    // feature buffers
    float* B1 = (float*)carve((size_t)64 * n);          // y_a (dual) or shared y (seq)
    float* C  = (float*)carve((size_t)64 * n);          // layer-1 result / h
    bool dual1 = false;
    float* B2 = nullptr;
    {
        size_t need_dual = fixed_off + 3 * ((size_t)64 * n) * 4;
        if (ws_size >= need_dual) { B2 = (float*)carve((size_t)64 * n); dual1 = true; }
    }

    const int T = 256;
    auto cdiv = [](long long a, long long b) { return (unsigned)((a + b - 1) / b); };
    const unsigned nb = cdiv(n, 256);

    auto build_csr = [&](const int* src, const int* dst, int E,
                         int* rowptr, int* col, float* dinv) {
        zero_int_kernel<<<cdiv(n, T), T, 0, stream>>>(deg, n);
        zero_int_kernel<<<1, 256, 0, stream>>>(bcnt, nbuk);
        bhist_kernel<<<cdiv(E, (long long)T * 16), T, 0, stream>>>(dst, bcnt, E, shift, nbuk);
        bscan_kernel<<<1, 256, 0, stream>>>(bcnt, bcursor, nbuk);
        hist_kernel<<<cdiv(E, T), T, 0, stream>>>(dst, deg, E);
        scan1_kernel<<<nb, 256, 0, stream>>>(deg, rowptr, partials, n);
        scan2_kernel<<<1, 64, 0, stream>>>(partials, nb);
        scan3_kernel<<<nb, 256, 0, stream>>>(rowptr, partials, cursor, deg, dinv, n, E);
        bfill_kernel<<<cdiv(E, BF_CHUNK), T, 0, stream>>>(src, dst, bcursor, pairs, E, shift, nbuk);
        lfill_kernel<<<cdiv(E, T), T, 0, stream>>>(pairs, cursor, col, E);
    };

    build_csr(eia, eia + Ea, Ea, rowptr_a, col_a, dinv_a);
    build_csr(eib, eib + Eb, Eb, rowptr_b, col_b, dinv_b);

    const unsigned AGG_GRID = 2048;

    // ---- layer 1 ----
    if (dual1) {
        gemm2_scale_kernel<64><<<cdiv(n, 64), T, 0, stream>>>(x, W1a, W1b, dinv_a, dinv_b, B1, B2, n);
        agg64_kernel<0><<<AGG_GRID, T, 0, stream>>>(B1, rowptr_a, col_a, dinv_a, nullptr, nullptr, nullptr, C, n);
        agg64_kernel<1><<<AGG_GRID, T, 0, stream>>>(B2, rowptr_b, col_b, dinv_b, C, b1a, b1b, C, n);
    } else {
        gemm_scale_kernel<64><<<cdiv(n, 64), T, 0, stream>>>(x, W1a, dinv_a, B1, n);
        agg64_kernel<0><<<AGG_GRID, T, 0, stream>>>(B1, rowptr_a, col_a, dinv_a, nullptr, nullptr, nullptr, C, n);
        gemm_scale_kernel<64><<<cdiv(n, 64), T, 0, stream>>>(x, W1b, dinv_b, B1, n);
        agg64_kernel<1><<<AGG_GRID, T, 0, stream>>>(B1, rowptr_b, col_b, dinv_b, C, b1a, b1b, C, n);
    }

    // ---- layer 2 (input = C); y2a/y2b/D fit inside B1 (64n) ----
    float* y2a = B1;
    float* y2b = B1 + (size_t)16 * n;
    float* D   = B1 + (size_t)32 * n;
    gemm2_scale_kernel<16><<<cdiv(n, 64), T, 0, stream>>>(C, W2a, W2b, dinv_a, dinv_b, y2a, y2b, n);
    agg16_kernel<0><<<AGG_GRID, T, 0, stream>>>(y2a, rowptr_a, col_a, dinv_a, nullptr, nullptr, nullptr, D, n);
    agg16_kernel<1><<<AGG_GRID, T, 0, stream>>>(y2b, rowptr_b, col_b, dinv_b, D, b2a, b2b, out, n);
}

// Round 4
// 438.542 us; speedup vs baseline: 1.7444x; 1.1026x over previous
//
#include <hip/hip_runtime.h>

#define LDS_XPAD 68
#define MAXBUK 256
#define BF_CHUNK 2048

typedef unsigned short ushort_t;
typedef unsigned int uint_t;

__device__ __forceinline__ ushort_t f2bf(float x) {
    uint_t u = __float_as_uint(x);
    uint_t r = (u + 0x7FFFu + ((u >> 16) & 1u)) >> 16;
    return (ushort_t)r;
}
__device__ __forceinline__ float bf2f(ushort_t h) {
    return __uint_as_float((uint_t)h << 16);
}

__global__ void zero_int_kernel(int* p, int n) {
    int i = blockIdx.x * blockDim.x + threadIdx.x;
    if (i < n) p[i] = 0;
}

// fused: bucket histogram (LDS) + per-node degree (global atomics), one pass over dst
__global__ void bhist_kernel(const int* __restrict__ dst, int* __restrict__ bcnt,
                             int* __restrict__ deg, int E, int shift, int nbuk) {
    __shared__ int h[MAXBUK];
    for (int i = threadIdx.x; i < nbuk; i += blockDim.x) h[i] = 0;
    __syncthreads();
    int stride = gridDim.x * blockDim.x;
    for (int e = blockIdx.x * blockDim.x + threadIdx.x; e < E; e += stride) {
        int d = dst[e];
        atomicAdd(&h[d >> shift], 1);
        atomicAdd(&deg[d], 1);
    }
    __syncthreads();
    for (int i = threadIdx.x; i < nbuk; i += blockDim.x)
        if (h[i]) atomicAdd(&bcnt[i], h[i]);
}

__global__ void bscan_kernel(const int* __restrict__ bcnt, int* __restrict__ bcursor, int nbuk) {
    __shared__ int s[256];
    int t = threadIdx.x;
    int v = (t < nbuk) ? bcnt[t] : 0;
    s[t] = v;
    __syncthreads();
    #pragma unroll
    for (int d = 1; d < 256; d <<= 1) {
        int u = (t >= d) ? s[t - d] : 0;
        __syncthreads();
        s[t] += u;
        __syncthreads();
    }
    if (t < nbuk) bcursor[t] = s[t] - v;   // exclusive
}

__global__ void bfill_kernel(const int* __restrict__ src, const int* __restrict__ dst,
                             int* __restrict__ bcursor, int2* __restrict__ pairs,
                             int E, int shift, int nbuk) {
    __shared__ int cnt[MAXBUK];
    __shared__ int base[MAXBUK];
    __shared__ int off[MAXBUK];
    const int t = threadIdx.x;
    const long long e0 = (long long)blockIdx.x * BF_CHUNK;
    const int nedge = (int)min((long long)BF_CHUNK, (long long)E - e0);
    for (int i = t; i < nbuk; i += 256) cnt[i] = 0;
    __syncthreads();
    for (int i = t; i < nedge; i += 256) atomicAdd(&cnt[dst[e0 + i] >> shift], 1);
    __syncthreads();
    for (int i = t; i < nbuk; i += 256) {
        off[i] = 0;
        base[i] = cnt[i] ? atomicAdd(&bcursor[i], cnt[i]) : 0;
    }
    __syncthreads();
    for (int i = t; i < nedge; i += 256) {
        int d = dst[e0 + i];
        int b = d >> shift;
        int p = base[b] + atomicAdd(&off[b], 1);
        pairs[p] = make_int2(src[e0 + i], d);
    }
}

__global__ void lfill_kernel(const int2* __restrict__ pairs, int* __restrict__ cursor,
                             int* __restrict__ col, int E) {
    int e = blockIdx.x * blockDim.x + threadIdx.x;
    if (e < E) {
        int2 p = pairs[e];
        int pos = atomicAdd(&cursor[p.y], 1);
        col[pos] = p.x;
    }
}

__global__ void scan1_kernel(const int* __restrict__ deg, int* __restrict__ rowptr,
                             int* __restrict__ partials, int n) {
    __shared__ int s[256];
    int i = blockIdx.x * 256 + threadIdx.x;
    int v = (i < n) ? deg[i] : 0;
    s[threadIdx.x] = v;
    __syncthreads();
    #pragma unroll
    for (int d = 1; d < 256; d <<= 1) {
        int t = (threadIdx.x >= d) ? s[threadIdx.x - d] : 0;
        __syncthreads();
        s[threadIdx.x] += t;
        __syncthreads();
    }
    if (i < n) rowptr[i] = s[threadIdx.x] - v;
    if (threadIdx.x == 255) partials[blockIdx.x] = s[255];
}

__global__ void scan2_kernel(int* partials, int nb) {
    int lane = threadIdx.x;
    int acc = 0;
    for (int base = 0; base < nb; base += 64) {
        int i = base + lane;
        int v = (i < nb) ? partials[i] : 0;
        int s = v;
        #pragma unroll
        for (int d = 1; d < 64; d <<= 1) {
            int t = __shfl_up(s, d);
            if (lane >= d) s += t;
        }
        if (i < nb) partials[i] = acc + s - v;
        acc += __shfl(s, 63);
    }
}

__global__ void scan3_kernel(int* __restrict__ rowptr, const int* __restrict__ partials,
                             int* __restrict__ cursor, const int* __restrict__ deg,
                             float* __restrict__ dinv, int n, int E) {
    int i = blockIdx.x * 256 + threadIdx.x;
    if (i < n) {
        int v = rowptr[i] + partials[blockIdx.x];
        rowptr[i] = v;
        cursor[i] = v;
        dinv[i] = rsqrtf((float)(deg[i] + 1));
    }
    if (i == 0) rowptr[n] = E;
}

// ---- dual-weight GEMM (layer 1, M=64): ya/yb written as bf16 ----
__global__ void gemm2_scale_bf16_kernel(const float* __restrict__ X,
                                        const float* __restrict__ Wa, const float* __restrict__ Wb,
                                        const float* __restrict__ dinva, const float* __restrict__ dinvb,
                                        ushort_t* __restrict__ ya, ushort_t* __restrict__ yb, int n) {
    constexpr int M = 64;
    __shared__ float xs[64 * LDS_XPAD];
    __shared__ float wsa[64 * M];
    __shared__ float wsb[64 * M];
    const int tid = threadIdx.x;
    const int row = tid >> 2;
    const int cg  = tid & 3;
    const int grow = blockIdx.x * 64 + row;

    {
        float4 v0, v1, v2, v3;
        if (grow < n) {
            const float4* xr = reinterpret_cast<const float4*>(X + (size_t)grow * 64 + cg * 16);
            v0 = xr[0]; v1 = xr[1]; v2 = xr[2]; v3 = xr[3];
        } else {
            v0 = v1 = v2 = v3 = make_float4(0.f, 0.f, 0.f, 0.f);
        }
        float4* xd = reinterpret_cast<float4*>(&xs[row * LDS_XPAD + cg * 16]);
        xd[0] = v0; xd[1] = v1; xd[2] = v2; xd[3] = v3;
    }
    {
        const float4* sa = reinterpret_cast<const float4*>(Wa);
        const float4* sb = reinterpret_cast<const float4*>(Wb);
        float4* da = reinterpret_cast<float4*>(wsa);
        float4* db = reinterpret_cast<float4*>(wsb);
        #pragma unroll
        for (int i = 0; i < 4; ++i) {
            int idx = tid + i * 256;
            da[idx] = sa[idx]; db[idx] = sb[idx];
        }
    }
    __syncthreads();

    constexpr int CPT = 16;
    float acca[CPT], accb[CPT];
    #pragma unroll
    for (int j = 0; j < CPT; ++j) { acca[j] = 0.0f; accb[j] = 0.0f; }

    for (int k = 0; k < 64; ++k) {
        float xk = xs[row * LDS_XPAD + k];
        #pragma unroll
        for (int j = 0; j < CPT; ++j) {
            acca[j] += xk * wsa[k * M + cg * CPT + j];
            accb[j] += xk * wsb[k * M + cg * CPT + j];
        }
    }

    if (grow < n) {
        float sa = dinva[grow], sb = dinvb[grow];
        uint_t pka[8], pkb[8];
        #pragma unroll
        for (int j = 0; j < 8; ++j) {
            pka[j] = (uint_t)f2bf(acca[2 * j] * sa) | ((uint_t)f2bf(acca[2 * j + 1] * sa) << 16);
            pkb[j] = (uint_t)f2bf(accb[2 * j] * sb) | ((uint_t)f2bf(accb[2 * j + 1] * sb) << 16);
        }
        uint4* pa = reinterpret_cast<uint4*>(ya + (size_t)grow * 64 + cg * 16);
        uint4* pb = reinterpret_cast<uint4*>(yb + (size_t)grow * 64 + cg * 16);
        pa[0] = make_uint4(pka[0], pka[1], pka[2], pka[3]);
        pa[1] = make_uint4(pka[4], pka[5], pka[6], pka[7]);
        pb[0] = make_uint4(pkb[0], pkb[1], pkb[2], pkb[3]);
        pb[1] = make_uint4(pkb[4], pkb[5], pkb[6], pkb[7]);
    }
}

// ---- dual-weight GEMM (layer 2, M=16): f32 out ----
__global__ void gemm2_scale_f32_kernel(const float* __restrict__ X,
                                       const float* __restrict__ Wa, const float* __restrict__ Wb,
                                       const float* __restrict__ dinva, const float* __restrict__ dinvb,
                                       float* __restrict__ ya, float* __restrict__ yb, int n) {
    constexpr int M = 16;
    __shared__ float xs[64 * LDS_XPAD];
    __shared__ float wsa[64 * M];
    __shared__ float wsb[64 * M];
    const int tid = threadIdx.x;
    const int row = tid >> 2;
    const int cg  = tid & 3;
    const int grow = blockIdx.x * 64 + row;

    {
        float4 v0, v1, v2, v3;
        if (grow < n) {
            const float4* xr = reinterpret_cast<const float4*>(X + (size_t)grow * 64 + cg * 16);
            v0 = xr[0]; v1 = xr[1]; v2 = xr[2]; v3 = xr[3];
        } else {
            v0 = v1 = v2 = v3 = make_float4(0.f, 0.f, 0.f, 0.f);
        }
        float4* xd = reinterpret_cast<float4*>(&xs[row * LDS_XPAD + cg * 16]);
        xd[0] = v0; xd[1] = v1; xd[2] = v2; xd[3] = v3;
    }
    {
        const float4* sa = reinterpret_cast<const float4*>(Wa);
        const float4* sb = reinterpret_cast<const float4*>(Wb);
        float4* da = reinterpret_cast<float4*>(wsa);
        float4* db = reinterpret_cast<float4*>(wsb);
        if (tid < 64 * M / 4) { da[tid] = sa[tid]; db[tid] = sb[tid]; }
    }
    __syncthreads();

    constexpr int CPT = 4;
    float acca[CPT], accb[CPT];
    #pragma unroll
    for (int j = 0; j < CPT; ++j) { acca[j] = 0.0f; accb[j] = 0.0f; }

    for (int k = 0; k < 64; ++k) {
        float xk = xs[row * LDS_XPAD + k];
        #pragma unroll
        for (int j = 0; j < CPT; ++j) {
            acca[j] += xk * wsa[k * M + cg * CPT + j];
            accb[j] += xk * wsb[k * M + cg * CPT + j];
        }
    }

    if (grow < n) {
        float sa = dinva[grow], sb = dinvb[grow];
        *reinterpret_cast<float4*>(ya + (size_t)grow * M + cg * CPT) =
            make_float4(acca[0] * sa, acca[1] * sa, acca[2] * sa, acca[3] * sa);
        *reinterpret_cast<float4*>(yb + (size_t)grow * M + cg * CPT) =
            make_float4(accb[0] * sb, accb[1] * sb, accb[2] * sb, accb[3] * sb);
    }
}

// ---- fused dual-relation aggregation, layer 1 (bf16 gathers, F=64) ----
// h[i] = relu(0.5*(dinva[i]*(ya[i]+sum_a) + dinvb[i]*(yb[i]+sum_b) + ba + bb))
__global__ void agg64_dual_kernel(const ushort_t* __restrict__ ya, const ushort_t* __restrict__ yb,
                                  const int* __restrict__ rpa, const int* __restrict__ cola,
                                  const float* __restrict__ dinva,
                                  const int* __restrict__ rpb, const int* __restrict__ colb,
                                  const float* __restrict__ dinvb,
                                  const float* __restrict__ ba, const float* __restrict__ bb,
                                  float* __restrict__ h, int n) {
    const int lane = threadIdx.x & 63;
    const int wid  = (blockIdx.x * blockDim.x + threadIdx.x) >> 6;
    const int nw   = (gridDim.x * blockDim.x) >> 6;
    const float bias = ba[lane] + bb[lane];
    for (int i = wid; i < n; i += nw) {
        float acca = bf2f(ya[(size_t)i * 64 + lane]);
        {
            const int e1 = rpa[i + 1];
            int e = rpa[i];
            for (; e + 4 <= e1; e += 4) {
                int s0 = cola[e], s1 = cola[e + 1], s2 = cola[e + 2], s3 = cola[e + 3];
                float g0 = bf2f(ya[(size_t)s0 * 64 + lane]);
                float g1 = bf2f(ya[(size_t)s1 * 64 + lane]);
                float g2 = bf2f(ya[(size_t)s2 * 64 + lane]);
                float g3 = bf2f(ya[(size_t)s3 * 64 + lane]);
                acca += g0 + g1 + g2 + g3;
            }
            for (; e < e1; ++e) acca += bf2f(ya[(size_t)cola[e] * 64 + lane]);
        }
        float accb = bf2f(yb[(size_t)i * 64 + lane]);
        {
            const int e1 = rpb[i + 1];
            int e = rpb[i];
            for (; e + 4 <= e1; e += 4) {
                int s0 = colb[e], s1 = colb[e + 1], s2 = colb[e + 2], s3 = colb[e + 3];
                float g0 = bf2f(yb[(size_t)s0 * 64 + lane]);
                float g1 = bf2f(yb[(size_t)s1 * 64 + lane]);
                float g2 = bf2f(yb[(size_t)s2 * 64 + lane]);
                float g3 = bf2f(yb[(size_t)s3 * 64 + lane]);
                accb += g0 + g1 + g2 + g3;
            }
            for (; e < e1; ++e) accb += bf2f(yb[(size_t)colb[e] * 64 + lane]);
        }
        float v = 0.5f * (acca * dinva[i] + accb * dinvb[i] + bias);
        h[(size_t)i * 64 + lane] = fmaxf(v, 0.0f);
    }
}

// ---- fused dual-relation aggregation, layer 2 (f32, F=16) ----
__global__ void agg16_dual_kernel(const float* __restrict__ za, const float* __restrict__ zb,
                                  const int* __restrict__ rpa, const int* __restrict__ cola,
                                  const float* __restrict__ dinva,
                                  const int* __restrict__ rpb, const int* __restrict__ colb,
                                  const float* __restrict__ dinvb,
                                  const float* __restrict__ ba, const float* __restrict__ bb,
                                  float* __restrict__ outp, int n) {
    const int lane = threadIdx.x & 15;
    const int gid  = (blockIdx.x * blockDim.x + threadIdx.x) >> 4;
    const int ng   = (gridDim.x * blockDim.x) >> 4;
    const float bias = ba[lane] + bb[lane];
    for (int i = gid; i < n; i += ng) {
        float acca = za[(size_t)i * 16 + lane];
        {
            const int e1 = rpa[i + 1];
            int e = rpa[i];
            for (; e + 4 <= e1; e += 4) {
                int s0 = cola[e], s1 = cola[e + 1], s2 = cola[e + 2], s3 = cola[e + 3];
                acca += za[(size_t)s0 * 16 + lane] + za[(size_t)s1 * 16 + lane]
                      + za[(size_t)s2 * 16 + lane] + za[(size_t)s3 * 16 + lane];
            }
            for (; e < e1; ++e) acca += za[(size_t)cola[e] * 16 + lane];
        }
        float accb = zb[(size_t)i * 16 + lane];
        {
            const int e1 = rpb[i + 1];
            int e = rpb[i];
            for (; e + 4 <= e1; e += 4) {
                int s0 = colb[e], s1 = colb[e + 1], s2 = colb[e + 2], s3 = colb[e + 3];
                accb += zb[(size_t)s0 * 16 + lane] + zb[(size_t)s1 * 16 + lane]
                      + zb[(size_t)s2 * 16 + lane] + zb[(size_t)s3 * 16 + lane];
            }
            for (; e < e1; ++e) accb += zb[(size_t)colb[e] * 16 + lane];
        }
        outp[(size_t)i * 16 + lane] = 0.5f * (acca * dinva[i] + accb * dinvb[i] + bias);
    }
}

extern "C" void kernel_launch(void* const* d_in, const int* in_sizes, int n_in,
                              void* d_out, int out_size, void* d_ws, size_t ws_size,
                              hipStream_t stream) {
    const float* x   = (const float*)d_in[0];
    const int*   eia = (const int*)d_in[1];
    const int*   eib = (const int*)d_in[2];
    const float* W1a = (const float*)d_in[3];
    const float* b1a = (const float*)d_in[4];
    const float* W1b = (const float*)d_in[5];
    const float* b1b = (const float*)d_in[6];
    const float* W2a = (const float*)d_in[7];
    const float* b2a = (const float*)d_in[8];
    const float* W2b = (const float*)d_in[9];
    const float* b2b = (const float*)d_in[10];
    float* out = (float*)d_out;

    const int n  = in_sizes[0] / 64;
    const int Ea = in_sizes[1] / 2;
    const int Eb = in_sizes[2] / 2;
    const int Emax = Ea > Eb ? Ea : Eb;

    int shift = 9;
    while ((((long long)n + (1LL << shift) - 1) >> shift) > MAXBUK) ++shift;
    const int nbuk = (int)(((long long)n + (1LL << shift) - 1) >> shift);

    char* wsp = (char*)d_ws;
    size_t off = 0;
    auto carve = [&](size_t elems) { void* p = wsp + off; off += ((elems + 3) & ~(size_t)3) * 4; return p; };
    float* dinv_a   = (float*)carve(n);
    float* dinv_b   = (float*)carve(n);
    int*   rowptr_a = (int*)carve(n + 1);
    int*   rowptr_b = (int*)carve(n + 1);
    int*   deg      = (int*)carve(n);
    int*   cursor   = (int*)carve(n);
    int*   partials = (int*)carve(1024);
    int*   bcnt     = (int*)carve(MAXBUK);
    int*   bcursor  = (int*)carve(MAXBUK);
    int*   col_a    = (int*)carve(Ea);
    int*   col_b    = (int*)carve(Eb);
    int2*  pairs    = (int2*)carve((size_t)Emax * 2);
    ushort_t* ya    = (ushort_t*)carve((size_t)32 * n);  // 64n bf16
    ushort_t* yb    = (ushort_t*)carve((size_t)32 * n);
    float* C        = (float*)carve((size_t)64 * n);     // layer-1 output h
    // layer-2 f32 projections reuse ya/yb regions (16n floats = 8*? fits in 32n uints)
    float* z2a = (float*)ya;
    float* z2b = (float*)yb;

    const int T = 256;
    auto cdiv = [](long long a, long long b) { return (unsigned)((a + b - 1) / b); };
    const unsigned nb = cdiv(n, 256);

    auto build_csr = [&](const int* src, const int* dst, int E,
                         int* rowptr, int* col, float* dinv) {
        zero_int_kernel<<<cdiv(n, T), T, 0, stream>>>(deg, n);
        zero_int_kernel<<<1, 256, 0, stream>>>(bcnt, nbuk);
        bhist_kernel<<<cdiv(E, (long long)T * 16), T, 0, stream>>>(dst, bcnt, deg, E, shift, nbuk);
        bscan_kernel<<<1, 256, 0, stream>>>(bcnt, bcursor, nbuk);
        scan1_kernel<<<nb, 256, 0, stream>>>(deg, rowptr, partials, n);
        scan2_kernel<<<1, 64, 0, stream>>>(partials, nb);
        scan3_kernel<<<nb, 256, 0, stream>>>(rowptr, partials, cursor, deg, dinv, n, E);
        bfill_kernel<<<cdiv(E, BF_CHUNK), T, 0, stream>>>(src, dst, bcursor, pairs, E, shift, nbuk);
        lfill_kernel<<<cdiv(E, T), T, 0, stream>>>(pairs, cursor, col, E);
    };

    build_csr(eia, eia + Ea, Ea, rowptr_a, col_a, dinv_a);
    build_csr(eib, eib + Eb, Eb, rowptr_b, col_b, dinv_b);

    const unsigned AGG_GRID = 2048;

    // ---- layer 1 ----
    gemm2_scale_bf16_kernel<<<cdiv(n, 64), T, 0, stream>>>(x, W1a, W1b, dinv_a, dinv_b, ya, yb, n);
    agg64_dual_kernel<<<AGG_GRID, T, 0, stream>>>(ya, yb, rowptr_a, col_a, dinv_a,
                                                  rowptr_b, col_b, dinv_b, b1a, b1b, C, n);

    // ---- layer 2 ----
    gemm2_scale_f32_kernel<<<cdiv(n, 64), T, 0, stream>>>(C, W2a, W2b, dinv_a, dinv_b, z2a, z2b, n);
    agg16_dual_kernel<<<AGG_GRID, T, 0, stream>>>(z2a, z2b, rowptr_a, col_a, dinv_a,
                                                  rowptr_b, col_b, dinv_b, b2a, b2b, out, n);
}